// Round 3
// baseline (533.167 us; speedup 1.0000x reference)
//
#include <hip/hip_runtime.h>

#define NN 256
#define CC 16
#define OC 288          // 18*16 output channels (72 float4)

typedef unsigned long long u64;

__device__ __forceinline__ void add4(float4& a, const float4 b) {
    a.x += b.x; a.y += b.y; a.z += b.z; a.w += b.w;
}
__device__ __forceinline__ void ds_acc4(float* p, const float4 x) {
    atomicAdd(p+0, x.x); atomicAdd(p+1, x.y); atomicAdd(p+2, x.z); atomicAdd(p+3, x.w);
}

// ---------------- K0: neighbor lists + bitmasks ----------------
__global__ void k_build_nbr(const float* __restrict__ A, short* __restrict__ nbr,
                            int* __restrict__ deg, u64* __restrict__ umask) {
    int a = blockIdx.x;
    int t = threadIdx.x;            // 0..255
    int lane = t & 63, wave = t >> 6;
    bool pred = A[a*NN + t] != 0.0f;
    u64 m = __ballot(pred);
    __shared__ int wcnt[4];
    if (lane == 0) { wcnt[wave] = __popcll(m); umask[a*4 + wave] = m; }
    __syncthreads();
    int off = 0;
    for (int w = 0; w < wave; ++w) off += wcnt[w];
    if (pred) {
        int pos = off + __popcll(m & ((1ull << lane) - 1ull));
        nbr[a*NN + pos] = (short)t;
    }
    if (t == 0) deg[a] = wcnt[0] + wcnt[1] + wcnt[2] + wcnt[3];
}

// ---------------- K_A: slab-major fused c1,c2,c3,c4,c9,c11 ----------------
// block = slab i (256 blocks, 512 threads = 8 waves; wave owns rows j = wave+8m).
// Per row j: if j in N(i): read full row (serves c3 + masked c1/c2/c4);
// else: gather union N(i)|N(j) chunks once, masked into c1/c2/c4.
// c3[i,:] and c4[:,i] accumulate in LDS (stride 19 to dodge bank conflicts).
__global__ __launch_bounds__(512) void k_slab(const float4* __restrict__ T4,
                                              const u64* __restrict__ umask,
                                              float4* __restrict__ out4) {
    int i = blockIdx.x;
    int t = threadIdx.x;
    int wave = t >> 6, lane = t & 63;
    int g = lane >> 2, v = lane & 3;      // 16 groups x 4 lanes (one chunk = 4xfloat4)

    __shared__ u64 masks[NN][4];          // 8 KB
    __shared__ float c3a[NN*19];          // ~19 KB
    __shared__ float c4a[NN*19];          // ~19 KB
    __shared__ short lists[8][256];       // 4 KB (per-wave union list)

    for (int idx = t; idx < NN*4; idx += 512) ((u64*)masks)[idx] = umask[idx];
    for (int idx = t; idx < NN*19; idx += 512) { c3a[idx] = 0.f; c4a[idx] = 0.f; }
    __syncthreads();

    const u64 mi0 = masks[i][0], mi1 = masks[i][1], mi2 = masks[i][2], mi3 = masks[i][3];

    for (int j = wave; j < NN; j += 8) {
        const float4* row = T4 + ((size_t)(i*NN + j) << 10);
        u64 mj0 = masks[j][0], mj1 = masks[j][1], mj2 = masks[j][2], mj3 = masks[j][3];
        u64 miw[4] = {mi0, mi1, mi2, mi3};
        u64 mjw[4] = {mj0, mj1, mj2, mj3};
        bool typeA = (miw[j >> 6] >> (j & 63)) & 1;
        float4 a1 = {0,0,0,0}, a2 = {0,0,0,0};

        if (typeA) {
            #pragma unroll
            for (int base = 0; base < NN; base += 32) {
                const int wq = base >> 6, sh = base & 63;
                int k0 = base + g, k1 = base + 16 + g;
                float4 x0 = row[(k0 << 2) + v];
                float4 x1 = row[(k1 << 2) + v];
                int b0 = sh + g;
                bool m1a = (miw[wq] >> b0) & 1, m1b = (miw[wq] >> (b0+16)) & 1;
                bool m2a = (mjw[wq] >> b0) & 1, m2b = (mjw[wq] >> (b0+16)) & 1;
                if (m1a) add4(a1, x0);
                if (m1b) add4(a1, x1);
                if (m2a) { add4(a2, x0); ds_acc4(&c4a[k0*19 + v*4], x0); }
                if (m2b) { add4(a2, x1); ds_acc4(&c4a[k1*19 + v*4], x1); }
                ds_acc4(&c3a[k0*19 + v*4], x0);
                ds_acc4(&c3a[k1*19 + v*4], x1);
            }
        } else {
            u64 u0 = mi0|mj0, u1 = mi1|mj1, u2 = mi2|mj2, u3 = mi3|mj3;
            int n0 = __popcll(u0), n1 = __popcll(u1), n2 = __popcll(u2), n3 = __popcll(u3);
            int n = n0 + n1 + n2 + n3;
            u64 below = (1ull << lane) - 1ull;
            if ((u0 >> lane) & 1)
                lists[wave][__popcll(u0 & below)] =
                    (short)(lane | (int)((mi0>>lane)&1)<<8 | (int)((mj0>>lane)&1)<<9);
            if ((u1 >> lane) & 1)
                lists[wave][n0 + __popcll(u1 & below)] =
                    (short)((64+lane) | (int)((mi1>>lane)&1)<<8 | (int)((mj1>>lane)&1)<<9);
            if ((u2 >> lane) & 1)
                lists[wave][n0+n1 + __popcll(u2 & below)] =
                    (short)((128+lane) | (int)((mi2>>lane)&1)<<8 | (int)((mj2>>lane)&1)<<9);
            if ((u3 >> lane) & 1)
                lists[wave][n0+n1+n2 + __popcll(u3 & below)] =
                    (short)((192+lane) | (int)((mi3>>lane)&1)<<8 | (int)((mj3>>lane)&1)<<9);

            for (int tt = 0; tt < n; tt += 32) {
                int e0 = tt + g, e1 = tt + 16 + g;
                int s0 = (e0 < n) ? (int)lists[wave][e0] : -1;
                int s1 = (e1 < n) ? (int)lists[wave][e1] : -1;
                if (s0 >= 0) {
                    int k = s0 & 255; float4 x = row[(k << 2) + v];
                    if (s0 & 256) add4(a1, x);
                    if (s0 & 512) { add4(a2, x); ds_acc4(&c4a[k*19 + v*4], x); }
                }
                if (s1 >= 0) {
                    int k = s1 & 255; float4 x = row[(k << 2) + v];
                    if (s1 & 256) add4(a1, x);
                    if (s1 & 512) { add4(a2, x); ds_acc4(&c4a[k*19 + v*4], x); }
                }
            }
        }

        // c9 = T[i,j,i] (ch8), c11 = T[i,j,j] (ch10)
        size_t orow = (size_t)(i*NN + j) * 72;
        if (g == 0) out4[orow + 32 + v] = row[(i << 2) + v];
        if (g == 1) out4[orow + 40 + v] = row[(j << 2) + v];

        // butterfly reduce a1,a2 across 16 groups (lane bits 2..5)
        for (int off = 4; off < 64; off <<= 1) {
            a1.x += __shfl_xor(a1.x, off); a1.y += __shfl_xor(a1.y, off);
            a1.z += __shfl_xor(a1.z, off); a1.w += __shfl_xor(a1.w, off);
            a2.x += __shfl_xor(a2.x, off); a2.y += __shfl_xor(a2.y, off);
            a2.z += __shfl_xor(a2.z, off); a2.w += __shfl_xor(a2.w, off);
        }
        if (g == 0) {
            out4[orow + 0 + v] = a1;                          // c1[i,j]
            out4[(size_t)(j*NN + i) * 72 + 4 + v] = a2;       // c2[j,i]
        }
    }

    __syncthreads();
    // flush c3[i,:] (ch2) and c4[:,i] (ch3)
    for (int idx = t; idx < NN*4; idx += 512) {
        int k = idx >> 2, q = idx & 3;
        float4 x3 = {c3a[k*19+q*4+0], c3a[k*19+q*4+1], c3a[k*19+q*4+2], c3a[k*19+q*4+3]};
        float4 x4 = {c4a[k*19+q*4+0], c4a[k*19+q*4+1], c4a[k*19+q*4+2], c4a[k*19+q*4+3]};
        out4[(size_t)(i*NN + k)*72 + 8  + q] = x3;
        out4[(size_t)(k*NN + i)*72 + 12 + q] = x4;
    }
}

// ---------------- K_B: c5, c6 + diagonals c7,c8,c10,c12 ----------------
// block = (a, b-quarter): 1024 blocks x 256 threads (4/CU -> tail-smoothed).
__global__ __launch_bounds__(256) void k_col(const float4* __restrict__ T4,
                                             const short* __restrict__ nbr,
                                             const int* __restrict__ deg,
                                             float4* __restrict__ out4) {
    int a = blockIdx.x >> 2;
    int qq = blockIdx.x & 3;
    int t = threadIdx.x;
    int g = t >> 2, v = t & 3;       // 64 groups
    int d = deg[a];
    __shared__ short nbs[NN];
    for (int e = t; e < d; e += 256) nbs[e] = nbr[a*NN + e];
    __syncthreads();

    const int b = qq*64 + g;
    const int qslot = qq*256 + t;    // float4 slot in row; b = slot>>2, v = slot&3
    float4 a5 = {0,0,0,0};
    float4 a6 = {0,0,0,0};
    #pragma unroll 2
    for (int e = 0; e < d; ++e) {
        int i = nbs[e];
        float4 x5 = T4[((size_t)(i*NN + a) << 10) + qslot];          // T[i,a,b,:]
        float4 x6 = T4[((size_t)i << 18) + (b << 10) + (a << 2) + v];// T[i,b,a,:]
        add4(a5, x5); add4(a6, x6);
    }
    float4 d7  = T4[((size_t)(a*NN + a) << 10) + qslot];             // T[a,a,b,:]
    float4 d8  = T4[((size_t)(b*NN + b) << 10) + (a << 2) + v];      // T[b,b,a,:]
    float4 d10 = T4[((size_t)(b*NN + a) << 10) + (b << 2) + v];      // T[b,a,b,:]
    float4 d12 = T4[((size_t)(b*NN + a) << 10) + (a << 2) + v];      // T[b,a,a,:]

    size_t o = (size_t)(a*NN + b) * 72;
    out4[o + 16 + v] = a5;    // c5
    out4[o + 20 + v] = a6;    // c6
    out4[o + 24 + v] = d7;    // c7
    out4[o + 28 + v] = d8;    // c8
    out4[o + 36 + v] = d10;   // c10
    out4[o + 44 + v] = d12;   // c12
}

// ---------------- K_V: v1,v2,v3 from materialized c1,c2,c6 ----------------
__global__ void k_vsum(const float* __restrict__ out_ro,
                       const short* __restrict__ nbr, const int* __restrict__ deg,
                       float* __restrict__ vbuf) {
    int a = blockIdx.x;
    int t = threadIdx.x;            // 256
    int c = t & 15, p = t >> 4;
    int d = deg[a];
    float s1 = 0.f, s2 = 0.f, s3 = 0.f;
    for (int e = p; e < d; e += 16) {
        int b = nbr[a*NN + e];
        size_t o = (size_t)(a*NN + b) * OC;
        s1 += out_ro[o + 0  + c];   // c1
        s2 += out_ro[o + 16 + c];   // c2
        s3 += out_ro[o + 80 + c];   // c6
    }
    __shared__ float red[3][16][17];
    red[0][p][c] = s1; red[1][p][c] = s2; red[2][p][c] = s3;
    __syncthreads();
    if (t < 48) {
        int vv = t >> 4, cc = t & 15;
        float s = 0.f;
        for (int pp = 0; pp < 16; ++pp) s += red[vv][pp][cc];
        vbuf[(vv*NN + a)*CC + cc] = s;
    }
}

// ---------------- K_C: broadcast v's into channels 12..17 ----------------
__global__ __launch_bounds__(256) void k_broadcast(const float4* __restrict__ vb4,
                                                   float4* __restrict__ out4) {
    int a = blockIdx.x;
    int t = threadIdx.x;
    int v = t & 3, bl = t >> 2;
    float4 v1a = vb4[(0*NN + a)*4 + v];
    float4 v2a = vb4[(1*NN + a)*4 + v];
    float4 v3a = vb4[(2*NN + a)*4 + v];
    for (int b = bl; b < NN; b += 64) {
        float4 v1b = vb4[(0*NN + b)*4 + v];
        float4 v2b = vb4[(1*NN + b)*4 + v];
        float4 v3b = vb4[(2*NN + b)*4 + v];
        size_t ob = (size_t)(a*NN + b) * 72;
        out4[ob + 48 + v] = v1a;   // c13
        out4[ob + 52 + v] = v1b;   // c14
        out4[ob + 56 + v] = v2a;   // c15
        out4[ob + 60 + v] = v2b;   // c16
        out4[ob + 64 + v] = v3a;   // c17
        out4[ob + 68 + v] = v3b;   // c18
    }
}

extern "C" void kernel_launch(void* const* d_in, const int* in_sizes, int n_in,
                              void* d_out, int out_size, void* d_ws, size_t ws_size,
                              hipStream_t stream) {
    const float* T = (const float*)d_in[0];   // (256,256,256,16) f32
    const float* A = (const float*)d_in[1];   // (256,256) f32 {0,1} symmetric
    float* out = (float*)d_out;

    // ws: umask u64[256][4] | nbr short[256*256] | deg int[256] | vbuf f32[3*256*16]
    char* w = (char*)d_ws;
    u64*   umask = (u64*)w;                   w += NN*4*sizeof(u64);
    short* nbr   = (short*)w;                 w += NN*NN*sizeof(short);
    int*   deg   = (int*)w;                   w += NN*sizeof(int);
    float* vbuf  = (float*)w;

    hipLaunchKernelGGL(k_build_nbr, dim3(NN),   dim3(NN),  0, stream, A, nbr, deg, umask);
    hipLaunchKernelGGL(k_slab,      dim3(NN),   dim3(512), 0, stream,
                       (const float4*)T, umask, (float4*)out);
    hipLaunchKernelGGL(k_col,       dim3(NN*4), dim3(256), 0, stream,
                       (const float4*)T, nbr, deg, (float4*)out);
    hipLaunchKernelGGL(k_vsum,      dim3(NN),   dim3(256), 0, stream, out, nbr, deg, vbuf);
    hipLaunchKernelGGL(k_broadcast, dim3(NN),   dim3(256), 0, stream,
                       (const float4*)vbuf, (float4*)out);
}

// Round 4
// 485.715 us; speedup vs baseline: 1.0977x; 1.0977x over previous
//
#include <hip/hip_runtime.h>

#define NN 256
#define CC 16
#define OC 288          // 18*16 output channels (72 float4)

typedef unsigned long long u64;
typedef unsigned int u32;

__device__ __forceinline__ void add4(float4& a, const float4 b) {
    a.x += b.x; a.y += b.y; a.z += b.z; a.w += b.w;
}

// position of i-th set bit of m (valid when i < popc(m)); branchless binary search
__device__ __forceinline__ int nthbit(u32 m, int i) {
    int pos = 0, c;
    c = __popc(m & 0xFFFFu); if (i >= c) { i -= c; pos = 16; m >>= 16; }
    c = __popc(m & 0xFFu);   if (i >= c) { i -= c; pos += 8; m >>= 8; }
    c = __popc(m & 0xFu);    if (i >= c) { i -= c; pos += 4; m >>= 4; }
    c = __popc(m & 0x3u);    if (i >= c) { i -= c; pos += 2; m >>= 2; }
    if (i >= (int)(m & 1u)) pos += 1;
    return pos;
}

// ---------------- K0: neighbor lists + bitmasks ----------------
__global__ void k_build_nbr(const float* __restrict__ A, short* __restrict__ nbr,
                            int* __restrict__ deg, u64* __restrict__ umask) {
    int a = blockIdx.x;
    int t = threadIdx.x;            // 0..255
    int lane = t & 63, wave = t >> 6;
    bool pred = A[a*NN + t] != 0.0f;
    u64 m = __ballot(pred);
    __shared__ int wcnt[4];
    if (lane == 0) { wcnt[wave] = __popcll(m); umask[a*4 + wave] = m; }
    __syncthreads();
    int off = 0;
    for (int w = 0; w < wave; ++w) off += wcnt[w];
    if (pred) {
        int pos = off + __popcll(m & ((1ull << lane) - 1ull));
        nbr[a*NN + pos] = (short)t;
    }
    if (t == 0) deg[a] = wcnt[0] + wcnt[1] + wcnt[2] + wcnt[3];
}

// ---------------- K_slab: c1,c2,c3,c4 + diagonals c7..c12 ----------------
// block = slab p (256 blocks x 512 threads = 8 waves).
// Wave w exclusively owns chunk range [32w, 32w+32) -> c3a/c4a LDS accumulation
// is race-free with plain RMW (no atomics). Per row q: union-masked gather of
// N(p)|N(q)|{p,q} chunks in the wave's range; full row when A[p,q] or q==p.
__global__ __launch_bounds__(512) void k_slab(const float4* __restrict__ T4,
                                              const u64* __restrict__ umask,
                                              float4* __restrict__ out4) {
    int p = blockIdx.x;
    int t = threadIdx.x;
    int w = t >> 6, lane = t & 63, g = lane >> 2, v = lane & 3;

    __shared__ u64   masks[NN][4];       // 8 KB
    __shared__ float c3a[NN*20];         // 20 KB (chunk stride 20 floats: pad vs banks)
    __shared__ float c4a[NN*20];         // 20 KB
    __shared__ float p1[8][64][16];      // 32 KB  c1 partials [wave][row][c]
    __shared__ float p2[8][64][16];      // 32 KB  c2 partials

    for (int idx = t; idx < NN*4; idx += 512) ((u64*)masks)[idx] = umask[idx];
    for (int idx = t; idx < NN*20; idx += 512) { c3a[idx] = 0.f; c4a[idx] = 0.f; }
    __syncthreads();

    const int kbase = w*32;
    const int wsh = (w & 1)*32;
    const u32 mi32 = (u32)(masks[p][w >> 1] >> wsh);   // N(p) restricted to range
    const u64 mp0 = masks[p][0], mp1 = masks[p][1], mp2 = masks[p][2], mp3 = masks[p][3];
    const float4* slab = T4 + ((size_t)p << 18);

    for (int tile = 0; tile < 4; ++tile) {
        u64 mpw = (tile==0) ? mp0 : (tile==1) ? mp1 : (tile==2) ? mp2 : mp3;
        #pragma unroll 2
        for (int r = 0; r < 64; ++r) {
            int q = tile*64 + r;
            bool typeA = (mpw >> r) & 1;
            u32 mj32 = (u32)(masks[q][w >> 1] >> wsh);
            u32 um = mi32 | mj32;
            if ((p >> 5) == w) um |= 1u << (p & 31);
            if ((q >> 5) == w) um |= 1u << (q & 31);
            bool fullrow = typeA || (q == p);
            if (fullrow) um = 0xFFFFFFFFu;
            int n = __popc(um);

            const float4* row = slab + ((size_t)q << 10);

            // two slots per lane-group: g-th and (16+g)-th set bit
            int  kl0 = nthbit(um, g);
            int  kl1 = nthbit(um, 16 + g);
            bool va0 = g < n;
            bool va1 = (16 + g) < n;
            int  k0 = kbase + kl0, k1 = kbase + kl1;
            float4 x0 = {0,0,0,0}, x1 = {0,0,0,0};
            if (va0) x0 = row[(k0 << 2) + v];
            if (va1) x1 = row[(k1 << 2) + v];

            float4 r1 = {0,0,0,0}, r2 = {0,0,0,0};
            bool p0 = va0 && ((mi32 >> kl0) & 1), q0 = va0 && ((mj32 >> kl0) & 1);
            bool p1f = va1 && ((mi32 >> kl1) & 1), q1 = va1 && ((mj32 >> kl1) & 1);
            if (p0) add4(r1, x0);
            if (p1f) add4(r1, x1);
            if (q0) add4(r2, x0);
            if (q1) add4(r2, x1);
            if (typeA) {
                if (va0) { float4* c = (float4*)&c3a[k0*20 + v*4]; float4 o = *c; add4(o, x0); *c = o; }
                if (va1) { float4* c = (float4*)&c3a[k1*20 + v*4]; float4 o = *c; add4(o, x1); *c = o; }
            }
            if (q0) { float4* c = (float4*)&c4a[k0*20 + v*4]; float4 o = *c; add4(o, x0); *c = o; }
            if (q1) { float4* c = (float4*)&c4a[k1*20 + v*4]; float4 o = *c; add4(o, x1); *c = o; }

            // diagonal extractions
            size_t opq = (size_t)(p*NN + q) * 72;
            size_t oqp = (size_t)(q*NN + p) * 72;
            if (va0 && k0 == p) { out4[opq + 32 + v] = x0; out4[oqp + 36 + v] = x0; } // c9,c10
            if (va1 && k1 == p) { out4[opq + 32 + v] = x1; out4[oqp + 36 + v] = x1; }
            if (va0 && k0 == q) { out4[opq + 40 + v] = x0; out4[oqp + 44 + v] = x0; } // c11,c12
            if (va1 && k1 == q) { out4[opq + 40 + v] = x1; out4[oqp + 44 + v] = x1; }
            if (q == p) {        // row (p,p): c7[p,k], c8[k,p]
                if (va0) { out4[(size_t)(p*NN + k0)*72 + 24 + v] = x0;
                           out4[(size_t)(k0*NN + p)*72 + 28 + v] = x0; }
                if (va1) { out4[(size_t)(p*NN + k1)*72 + 24 + v] = x1;
                           out4[(size_t)(k1*NN + p)*72 + 28 + v] = x1; }
            }

            // reduce r1,r2 across the 16 lane-groups (lane bits 2..5)
            for (int off = 4; off < 64; off <<= 1) {
                r1.x += __shfl_xor(r1.x, off); r1.y += __shfl_xor(r1.y, off);
                r1.z += __shfl_xor(r1.z, off); r1.w += __shfl_xor(r1.w, off);
                r2.x += __shfl_xor(r2.x, off); r2.y += __shfl_xor(r2.y, off);
                r2.z += __shfl_xor(r2.z, off); r2.w += __shfl_xor(r2.w, off);
            }
            if (g == 0) {
                *(float4*)&p1[w][r][v*4] = r1;
                *(float4*)&p2[w][r][v*4] = r2;
            }
        }
        __syncthreads();
        // finalize c1[p,q] / c2[q,p] for this tile's 64 rows
        {
            int half = t >> 8;            // 0 -> c1, 1 -> c2
            int it = t & 255;
            int r = it >> 2, vv = it & 3;
            int q = tile*64 + r;
            float4 s = {0,0,0,0};
            #pragma unroll
            for (int ww = 0; ww < 8; ++ww) {
                const float* src = half ? &p2[ww][r][vv*4] : &p1[ww][r][vv*4];
                add4(s, *(const float4*)src);
            }
            if (half == 0) out4[(size_t)(p*NN + q)*72 + 0 + vv] = s;
            else           out4[(size_t)(q*NN + p)*72 + 4 + vv] = s;
        }
        __syncthreads();
    }

    // flush c3[p,.] (ch2) and c4[.,p] (ch3)
    for (int idx = t; idx < NN*4; idx += 512) {
        int k = idx >> 2, vv = idx & 3;
        float4 x3 = *(const float4*)&c3a[k*20 + vv*4];
        float4 x4 = *(const float4*)&c4a[k*20 + vv*4];
        out4[(size_t)(p*NN + k)*72 + 8  + vv] = x3;
        out4[(size_t)(k*NN + p)*72 + 12 + vv] = x4;
    }
}

// ---------------- K_col: c5, c6 ----------------
// block = (a, b-quarter): 1024 blocks x 256 threads.
__global__ __launch_bounds__(256) void k_col(const float4* __restrict__ T4,
                                             const short* __restrict__ nbr,
                                             const int* __restrict__ deg,
                                             float4* __restrict__ out4) {
    int a = blockIdx.x >> 2;
    int qq = blockIdx.x & 3;
    int t = threadIdx.x;
    int g = t >> 2, v = t & 3;
    int d = deg[a];
    __shared__ short nbs[NN];
    for (int e = t; e < d; e += 256) nbs[e] = nbr[a*NN + e];
    __syncthreads();

    const int b = qq*64 + g;
    const int qslot = qq*256 + t;
    float4 a5 = {0,0,0,0};
    float4 a6 = {0,0,0,0};
    #pragma unroll 2
    for (int e = 0; e < d; ++e) {
        int i = nbs[e];
        float4 x5 = T4[((size_t)(i*NN + a) << 10) + qslot];           // T[i,a,b,:]
        float4 x6 = T4[((size_t)i << 18) + (b << 10) + (a << 2) + v]; // T[i,b,a,:]
        add4(a5, x5); add4(a6, x6);
    }
    size_t o = (size_t)(a*NN + b) * 72;
    out4[o + 16 + v] = a5;    // c5
    out4[o + 20 + v] = a6;    // c6
}

// ---------------- K_V: v1,v2,v3 from materialized c1,c2,c6 ----------------
__global__ void k_vsum(const float* __restrict__ out_ro,
                       const short* __restrict__ nbr, const int* __restrict__ deg,
                       float* __restrict__ vbuf) {
    int a = blockIdx.x;
    int t = threadIdx.x;            // 256
    int c = t & 15, p = t >> 4;
    int d = deg[a];
    float s1 = 0.f, s2 = 0.f, s3 = 0.f;
    for (int e = p; e < d; e += 16) {
        int b = nbr[a*NN + e];
        size_t o = (size_t)(a*NN + b) * OC;
        s1 += out_ro[o + 0  + c];   // c1
        s2 += out_ro[o + 16 + c];   // c2
        s3 += out_ro[o + 80 + c];   // c6
    }
    __shared__ float red[3][16][17];
    red[0][p][c] = s1; red[1][p][c] = s2; red[2][p][c] = s3;
    __syncthreads();
    if (t < 48) {
        int vv = t >> 4, cc = t & 15;
        float s = 0.f;
        for (int pp = 0; pp < 16; ++pp) s += red[vv][pp][cc];
        vbuf[(vv*NN + a)*CC + cc] = s;
    }
}

// ---------------- K_C: broadcast v's into channels 12..17 ----------------
__global__ __launch_bounds__(256) void k_broadcast(const float4* __restrict__ vb4,
                                                   float4* __restrict__ out4) {
    int a = blockIdx.x;
    int t = threadIdx.x;
    int v = t & 3, bl = t >> 2;
    float4 v1a = vb4[(0*NN + a)*4 + v];
    float4 v2a = vb4[(1*NN + a)*4 + v];
    float4 v3a = vb4[(2*NN + a)*4 + v];
    for (int b = bl; b < NN; b += 64) {
        float4 v1b = vb4[(0*NN + b)*4 + v];
        float4 v2b = vb4[(1*NN + b)*4 + v];
        float4 v3b = vb4[(2*NN + b)*4 + v];
        size_t ob = (size_t)(a*NN + b) * 72;
        out4[ob + 48 + v] = v1a;   // c13
        out4[ob + 52 + v] = v1b;   // c14
        out4[ob + 56 + v] = v2a;   // c15
        out4[ob + 60 + v] = v2b;   // c16
        out4[ob + 64 + v] = v3a;   // c17
        out4[ob + 68 + v] = v3b;   // c18
    }
}

extern "C" void kernel_launch(void* const* d_in, const int* in_sizes, int n_in,
                              void* d_out, int out_size, void* d_ws, size_t ws_size,
                              hipStream_t stream) {
    const float* T = (const float*)d_in[0];   // (256,256,256,16) f32
    const float* A = (const float*)d_in[1];   // (256,256) f32 {0,1} symmetric
    float* out = (float*)d_out;

    // ws: umask u64[256][4] | nbr short[256*256] | deg int[256] | vbuf f32[3*256*16]
    char* w = (char*)d_ws;
    u64*   umask = (u64*)w;                   w += NN*4*sizeof(u64);
    short* nbr   = (short*)w;                 w += NN*NN*sizeof(short);
    int*   deg   = (int*)w;                   w += NN*sizeof(int);
    float* vbuf  = (float*)w;

    hipLaunchKernelGGL(k_build_nbr, dim3(NN),   dim3(NN),  0, stream, A, nbr, deg, umask);
    hipLaunchKernelGGL(k_slab,      dim3(NN),   dim3(512), 0, stream,
                       (const float4*)T, umask, (float4*)out);
    hipLaunchKernelGGL(k_col,       dim3(NN*4), dim3(256), 0, stream,
                       (const float4*)T, nbr, deg, (float4*)out);
    hipLaunchKernelGGL(k_vsum,      dim3(NN),   dim3(256), 0, stream, out, nbr, deg, vbuf);
    hipLaunchKernelGGL(k_broadcast, dim3(NN),   dim3(256), 0, stream,
                       (const float4*)vbuf, (float4*)out);
}